// Round 9
// baseline (211.426 us; speedup 1.0000x reference)
//
#include <hip/hip_runtime.h>
#include <math.h>

// Problem constants
#define BB_ 8
#define C_ 512
#define C3_ 1536
#define HW_ 1024
#define NH_ 8
#define DH_ 64
#define HH_ 32
#define WW_ 32

typedef __attribute__((ext_vector_type(8))) short short8;
typedef __attribute__((ext_vector_type(4))) short short4v;
typedef __attribute__((ext_vector_type(8))) unsigned short ushort8;
typedef __attribute__((ext_vector_type(4))) unsigned short ushort4_t;
typedef __attribute__((ext_vector_type(4))) float f32x4;
typedef unsigned short ushort;

__device__ inline ushort f2bf(float f) {
  union { float f; unsigned u; } v;
  v.f = f;
  unsigned r = v.u + 0x7fffu + ((v.u >> 16) & 1u);
  return (ushort)(r >> 16);
}
__device__ inline float bf2f(ushort u) {
  union { unsigned u; float f; } v;
  v.u = ((unsigned)u) << 16;
  return v.f;
}

#define GLD16(gptr, lptr)                                                     \
  __builtin_amdgcn_global_load_lds(                                           \
      (const __attribute__((address_space(1))) unsigned int*)(gptr),          \
      (__attribute__((address_space(3))) unsigned int*)(lptr), 16, 0, 0)

// PV micro-op: D += Vt_frag(4 keys) x P_frag(4 keys), 16x16 output.
__device__ inline f32x4 pv_mfma(short4v vf, short4v pf, f32x4 acc) {
#if __has_builtin(__builtin_amdgcn_mfma_f32_16x16x16_bf16)
  return __builtin_amdgcn_mfma_f32_16x16x16_bf16(vf, pf, acc, 0, 0, 0);
#elif __has_builtin(__builtin_amdgcn_mfma_f32_16x16x16bf16_1k)
  return __builtin_amdgcn_mfma_f32_16x16x16bf16_1k(vf, pf, acc, 0, 0, 0);
#else
  short8 vf8 = {vf[0], vf[1], vf[2], vf[3], 0, 0, 0, 0};
  short8 pf8 = {pf[0], pf[1], pf[2], pf[3], 0, 0, 0, 0};
  return __builtin_amdgcn_mfma_f32_16x16x32_bf16(vf8, pf8, acc, 0, 0, 0);
#endif
}

// -------------------------------------------------------------------------
// K1 (prep): fused weight-cvt + x transpose(+pos) + qsum/ksum zeroing.
__global__ __launch_bounds__(256) void prep_kernel(
    const float* __restrict__ x, const float* __restrict__ pos,
    const float* __restrict__ qkv_w, const float* __restrict__ proj_w,
    const float* __restrict__ pw_w, ushort* __restrict__ t,
    ushort* __restrict__ xT, ushort* __restrict__ wts,
    float* __restrict__ sums) {
  const int bid = blockIdx.x;
  const int tid = threadIdx.x;
  if (bid >= 6144) {
    sums[(bid - 6144) * 256 + tid] = 0.f;
    return;
  }
  if (bid >= 1024) {
    int i = (bid - 1024) * 256 + tid;
    if (i < 786432) wts[i] = f2bf(qkv_w[i]);
    else if (i < 1048576) wts[i] = f2bf(proj_w[i - 786432]);
    else wts[i] = f2bf(pw_w[i - 1048576]);
    return;
  }
  __shared__ float tile[64][65];
  const int n0 = (bid & 15) * 64, c0 = ((bid >> 4) & 7) * 64, b = bid >> 7;
#pragma unroll
  for (int it = 0; it < 4; it++) {
    int c_l = (tid >> 4) + it * 16;
    int n_l4 = (tid & 15) * 4;
    float4 v = *(const float4*)&x[((size_t)(b * C_ + c0 + c_l)) * HW_ + n0 + n_l4];
    tile[c_l][n_l4 + 0] = v.x;
    tile[c_l][n_l4 + 1] = v.y;
    tile[c_l][n_l4 + 2] = v.z;
    tile[c_l][n_l4 + 3] = v.w;
  }
  __syncthreads();
#pragma unroll
  for (int it = 0; it < 4; it++) {
    int n_l = (tid >> 4) + it * 16;
    int c_l4 = (tid & 15) * 4;
    size_t token = (size_t)(b * HW_ + n0 + n_l);
    float4 pv = *(const float4*)&pos[(n0 + n_l) * C_ + c0 + c_l4];
    float xv0 = tile[c_l4 + 0][n_l], xv1 = tile[c_l4 + 1][n_l];
    float xv2 = tile[c_l4 + 2][n_l], xv3 = tile[c_l4 + 3][n_l];
    ushort4_t tb = {f2bf(xv0 + pv.x), f2bf(xv1 + pv.y), f2bf(xv2 + pv.z),
                    f2bf(xv3 + pv.w)};
    ushort4_t xb = {f2bf(xv0), f2bf(xv1), f2bf(xv2), f2bf(xv3)};
    *(ushort4_t*)&t[token * C_ + c0 + c_l4] = tb;
    *(ushort4_t*)&xT[token * C_ + c0 + c_l4] = xb;
  }
}

// -------------------------------------------------------------------------
// K2: qkv GEMM (m97 structure, 128x128). Epilogue: q/k bf16 + norm-sums;
// V -> transposed bf16 store into vt[bh*64+d][n].
__global__ __launch_bounds__(256) void gemm_qkv(
    const ushort* __restrict__ A, const ushort* __restrict__ Wm,
    ushort* __restrict__ out, ushort* __restrict__ vt,
    float* __restrict__ qsum, float* __restrict__ ksum) {
  const int N = C3_, K = C_;
  __shared__ alignas(16) ushort As[128 * 32];
  __shared__ alignas(16) ushort Bs[128 * 32];
  const int bn = blockIdx.x * 128, bm = blockIdx.y * 128;
  const int tid = threadIdx.x;
  const int w = tid >> 6, lane = tid & 63;
  const int wm = 64 * (w & 1), wn = 64 * (w >> 1);
  const int l15 = lane & 15, lq = lane >> 4;

  f32x4 acc[4][4];
#pragma unroll
  for (int i = 0; i < 4; i++)
#pragma unroll
    for (int j = 0; j < 4; j++) acc[i][j] = (f32x4){0.f, 0.f, 0.f, 0.f};

  const int srr = lane >> 2, sq1 = lane & 3;

  for (int k0 = 0; k0 < K; k0 += 32) {
    __syncthreads();
#pragma unroll
    for (int j = 0; j < 2; j++) {
      int r = 32 * w + 16 * j + srr;
      int q = (sq1 - (r >> 1)) & 3;
      GLD16(A + (size_t)(bm + r) * K + k0 + q * 8, &As[(32 * w + 16 * j) * 32]);
      GLD16(Wm + (size_t)(bn + r) * K + k0 + q * 8, &Bs[(32 * w + 16 * j) * 32]);
    }
    __syncthreads();
    short8 af[4], bf[4];
#pragma unroll
    for (int nt = 0; nt < 4; nt++) {
      int r = wm + nt * 16 + l15;
      af[nt] = *(const short8*)&As[r * 32 + (((lq + (r >> 1)) & 3) * 8)];
      int c = wn + nt * 16 + l15;
      bf[nt] = *(const short8*)&Bs[c * 32 + (((lq + (c >> 1)) & 3) * 8)];
    }
#pragma unroll
    for (int i = 0; i < 4; i++)
#pragma unroll
      for (int j = 0; j < 4; j++)
        acc[i][j] = __builtin_amdgcn_mfma_f32_16x16x32_bf16(af[i], bf[j],
                                                            acc[i][j], 0, 0, 0);
  }

  const int b = bm >> 10;
  if (bn < 1024) {
#pragma unroll
    for (int j = 0; j < 4; j++) {
      int c = bn + wn + j * 16 + l15;
      float ss = 0.f;
#pragma unroll
      for (int i = 0; i < 4; i++) {
#pragma unroll
        for (int r = 0; r < 4; r++) {
          int m = bm + wm + i * 16 + lq * 4 + r;
          float v = acc[i][j][r];
          ss += v * v;
          out[(size_t)m * N + c] = f2bf(v);
        }
      }
      ss += __shfl_xor(ss, 16);
      ss += __shfl_xor(ss, 32);
      if (lq == 0) {
        if (c < 512) atomicAdd(&qsum[b * 512 + c], ss);
        else atomicAdd(&ksum[b * 512 + c - 512], ss);
      }
    }
  } else {
#pragma unroll
    for (int j = 0; j < 4; j++) {
      int c = bn + wn + j * 16 + l15;
      int hd = c - 1024;
      ushort* vrow = vt + ((size_t)(b * 512 + hd)) * HW_;
#pragma unroll
      for (int i = 0; i < 4; i++) {
        int n0 = (bm & 1023) + wm + i * 16 + lq * 4;
        ushort4_t pv = {f2bf(acc[i][j][0]), f2bf(acc[i][j][1]),
                        f2bf(acc[i][j][2]), f2bf(acc[i][j][3])};
        *(ushort4_t*)&vrow[n0] = pv;
      }
    }
  }
}

// -------------------------------------------------------------------------
// bf16 MFMA GEMM 128x64 tiles. EPI 1: bf16 +bias token-major.
// EPI 2: f32 +bias +resid(bf16), NCHW store.
template <int EPI>
__global__ __launch_bounds__(256) void gemm_n64(
    const ushort* __restrict__ A, const ushort* __restrict__ Wm,
    const float* __restrict__ bias, void* __restrict__ outv,
    const ushort* __restrict__ resid, int N, int K) {
  __shared__ alignas(16) ushort As[128 * 32];
  __shared__ alignas(16) ushort Bs[64 * 32];
  const int bn = blockIdx.x * 64, bm = blockIdx.y * 128;
  const int tid = threadIdx.x;
  const int w = tid >> 6, lane = tid & 63;
  const int wm = 64 * (w & 1), wn = 32 * (w >> 1);
  const int l15 = lane & 15, lq = lane >> 4;

  f32x4 acc[4][2];
#pragma unroll
  for (int i = 0; i < 4; i++)
#pragma unroll
    for (int j = 0; j < 2; j++) acc[i][j] = (f32x4){0.f, 0.f, 0.f, 0.f};

  const int srr = lane >> 2, sq1 = lane & 3;

  for (int k0 = 0; k0 < K; k0 += 32) {
    __syncthreads();
#pragma unroll
    for (int j = 0; j < 2; j++) {
      int r = 32 * w + 16 * j + srr;
      int q = (sq1 - (r >> 1)) & 3;
      GLD16(A + (size_t)(bm + r) * K + k0 + q * 8, &As[(32 * w + 16 * j) * 32]);
    }
    {
      int r = 16 * w + srr;
      int q = (sq1 - (r >> 1)) & 3;
      GLD16(Wm + (size_t)(bn + r) * K + k0 + q * 8, &Bs[(16 * w) * 32]);
    }
    __syncthreads();
    short8 af[4], bf[2];
#pragma unroll
    for (int nt = 0; nt < 4; nt++) {
      int r = wm + nt * 16 + l15;
      af[nt] = *(const short8*)&As[r * 32 + (((lq + (r >> 1)) & 3) * 8)];
    }
#pragma unroll
    for (int j = 0; j < 2; j++) {
      int c = wn + j * 16 + l15;
      bf[j] = *(const short8*)&Bs[c * 32 + (((lq + (c >> 1)) & 3) * 8)];
    }
#pragma unroll
    for (int i = 0; i < 4; i++)
#pragma unroll
      for (int j = 0; j < 2; j++)
        acc[i][j] = __builtin_amdgcn_mfma_f32_16x16x32_bf16(af[i], bf[j],
                                                            acc[i][j], 0, 0, 0);
  }

#pragma unroll
  for (int i = 0; i < 4; i++) {
#pragma unroll
    for (int j = 0; j < 2; j++) {
      int c = bn + wn + j * 16 + l15;
      float bv = bias[c];
#pragma unroll
      for (int r = 0; r < 4; r++) {
        int m = bm + wm + i * 16 + lq * 4 + r;
        float v = acc[i][j][r] + bv;
        if (EPI == 1) {
          ((ushort*)outv)[(size_t)m * N + c] = f2bf(v);
        } else {
          int b = m >> 10, s = m & (HW_ - 1);
          ((float*)outv)[((size_t)(b * C_ + c)) * HW_ + s] =
              v + bf2f(resid[(size_t)m * C_ + c]);
        }
      }
    }
  }
}

// -------------------------------------------------------------------------
// K3: MFMA flash attention, 32 queries/wave (128/block, grid 512).
// Double-buffered direct-to-LDS staging, one barrier per K-tile. Each
// K/Vt fragment read feeds TWO MFMAs (q-group reuse) — halves LDS reads.
__global__ __launch_bounds__(256) void attn_mfma_kernel(
    const ushort* __restrict__ qkv, const ushort* __restrict__ vt,
    const float* __restrict__ qsum, const float* __restrict__ ksum,
    const float* __restrict__ temp, ushort* __restrict__ o) {
  __shared__ alignas(16) ushort Ks[2][64 * 64];   // [key][d], chunk-swizzled
  __shared__ alignas(16) ushort Vts[2][64 * 64];  // [d][key], chunk-swizzled
  __shared__ float sc_lds[64];

  const int tid = threadIdx.x;
  const int w = tid >> 6, lane = tid & 63;
  const int quad = lane >> 4, lcol = lane & 15;
  const int bh = blockIdx.x >> 3;
  const int qt = blockIdx.x & 7;
  const int b = bh >> 3, h = bh & 7;
  const int q0 = qt * 128;

  if (tid < 64) {
    float qs = qsum[b * 512 + h * 64 + tid];
    float ks = ksum[b * 512 + h * 64 + tid];
    float iq = 1.0f / fmaxf(sqrtf(qs), 1e-12f);
    float ik = 1.0f / fmaxf(sqrtf(ks), 1e-12f);
    sc_lds[tid] = iq * ik * temp[h];
  }

  const ushort* kg = qkv + (size_t)b * HW_ * C3_ + C_ + h * 64;
  const ushort* vg = vt + (size_t)(bh * 64) * HW_;

  // staging: 256 threads x 2 iters cover 64 rows x 8 chunks (of 8 bf16)
  const int srow0 = tid >> 3;  // 0..31
  const int sc = tid & 7;

  // prologue: stage tile 0 into buffer 0
#pragma unroll
  for (int it = 0; it < 2; it++) {
    int row = srow0 + it * 32;
    int scg = sc ^ (row & 7);
    GLD16(kg + (size_t)row * C3_ + scg * 8, &Ks[0][w * 512 + it * 2048]);
    GLD16(vg + (size_t)row * HW_ + scg * 8, &Vts[0][w * 512 + it * 2048]);
  }
  __syncthreads();

  // Q fragments for both q-groups (B-operand of S^T = K·Q^T), scales folded.
  short8 qf[2][2];
#pragma unroll
  for (int qg = 0; qg < 2; qg++) {
    const int m = q0 + w * 32 + qg * 16 + lcol;
    const ushort* qrow = qkv + ((size_t)(b * HW_ + m)) * C3_ + h * 64;
#pragma unroll
    for (int kc = 0; kc < 2; kc++) {
      union { short8 v; ushort u[8]; } pk;
#pragma unroll
      for (int j = 0; j < 8; j++) {
        int d = kc * 32 + quad * 8 + j;
        pk.u[j] = f2bf(bf2f(qrow[d]) * sc_lds[d]);
      }
      qf[qg][kc] = pk.v;
    }
  }

  f32x4 ot[2][4];
#pragma unroll
  for (int qg = 0; qg < 2; qg++)
#pragma unroll
    for (int dt = 0; dt < 4; dt++) ot[qg][dt] = (f32x4){0.f, 0.f, 0.f, 0.f};
  float lsum[2] = {0.f, 0.f};

  for (int kt = 0; kt < 16; kt++) {
    if (kt > 0) __syncthreads();  // drains GLD(kt) + prior buffer reads
    const int cur = kt & 1;
    if (kt + 1 < 16) {
      const int nxt = cur ^ 1;
#pragma unroll
      for (int it = 0; it < 2; it++) {
        int row = srow0 + it * 32;
        int scg = sc ^ (row & 7);
        GLD16(kg + (size_t)((kt + 1) * 64 + row) * C3_ + scg * 8,
              &Ks[nxt][w * 512 + it * 2048]);
        GLD16(vg + (size_t)row * HW_ + (kt + 1) * 64 + scg * 8,
              &Vts[nxt][w * 512 + it * 2048]);
      }
    }

    // S^T = K·Q^T for both q-groups; each K fragment read used twice
    f32x4 sfr[2][4];
#pragma unroll
    for (int qg = 0; qg < 2; qg++)
#pragma unroll
      for (int nt = 0; nt < 4; nt++) sfr[qg][nt] = (f32x4){0.f, 0.f, 0.f, 0.f};
#pragma unroll
    for (int kc = 0; kc < 2; kc++) {
#pragma unroll
      for (int nt = 0; nt < 4; nt++) {
        int row = nt * 16 + lcol;
        short8 kf = *(const short8*)
            &Ks[cur][row * 64 + (((kc * 4 + quad) ^ (row & 7)) * 8)];
        sfr[0][nt] = __builtin_amdgcn_mfma_f32_16x16x32_bf16(kf, qf[0][kc],
                                                             sfr[0][nt], 0, 0, 0);
        sfr[1][nt] = __builtin_amdgcn_mfma_f32_16x16x32_bf16(kf, qf[1][kc],
                                                             sfr[1][nt], 0, 0, 0);
      }
    }

    // exp (fixed max: scores bounded ~0.07) + per-lane sum + pack P
    short4v pk[2][4];
#pragma unroll
    for (int qg = 0; qg < 2; qg++) {
#pragma unroll
      for (int nt = 0; nt < 4; nt++) {
        ushort e0, e1, e2, e3;
        float f0 = __expf(sfr[qg][nt][0]);
        float f1 = __expf(sfr[qg][nt][1]);
        float f2 = __expf(sfr[qg][nt][2]);
        float f3 = __expf(sfr[qg][nt][3]);
        lsum[qg] += f0 + f1 + f2 + f3;
        e0 = f2bf(f0); e1 = f2bf(f1); e2 = f2bf(f2); e3 = f2bf(f3);
        pk[qg][nt] = (short4v){(short)e0, (short)e1, (short)e2, (short)e3};
      }
    }

    // O^T += V^T · P^T ; each Vt fragment read used twice
#pragma unroll
    for (int nt = 0; nt < 4; nt++) {
      int key = nt * 16 + quad * 4;
#pragma unroll
      for (int dt = 0; dt < 4; dt++) {
        int d = dt * 16 + lcol;
        short4v vf = *(const short4v*)
            &Vts[cur][d * 64 + (((key >> 3) ^ (d & 7)) * 8) + (key & 7)];
        ot[0][dt] = pv_mfma(vf, pk[0][nt], ot[0][dt]);
        ot[1][dt] = pv_mfma(vf, pk[1][nt], ot[1][dt]);
      }
    }
  }

#pragma unroll
  for (int qg = 0; qg < 2; qg++) {
    float s = lsum[qg];
    s += __shfl_xor(s, 16);
    s += __shfl_xor(s, 32);
    const float inv = 1.0f / s;
    const int m = q0 + w * 32 + qg * 16 + lcol;
    ushort* orow = o + ((size_t)(b * HW_ + m)) * C_ + h * 64;
#pragma unroll
    for (int dt = 0; dt < 4; dt++) {
      ushort4_t pkb = {f2bf(ot[qg][dt][0] * inv), f2bf(ot[qg][dt][1] * inv),
                       f2bf(ot[qg][dt][2] * inv), f2bf(ot[qg][dt][3] * inv)};
      *(ushort4_t*)&orow[dt * 16 + quad * 4] = pkb;
    }
  }
}

// -------------------------------------------------------------------------
// K5: LayerNorm, wave-per-token (no LDS, no barriers). bf16 in/out,
// residual xT bf16; writes y_bf in place over xT.
__global__ __launch_bounds__(256) void ln_residual_kernel(
    const ushort* __restrict__ po, const ushort* xT,
    const float* __restrict__ g, const float* __restrict__ bb, ushort* ybf) {
  const int wv = threadIdx.x >> 6, lane = threadIdx.x & 63;
  const int token = blockIdx.x * 4 + wv;
  const int c0 = lane * 8;
  ushort8 p8 = *(const ushort8*)&po[(size_t)token * C_ + c0];
  float v[8];
  float s = 0.f;
#pragma unroll
  for (int j = 0; j < 8; j++) {
    v[j] = bf2f(p8[j]);
    s += v[j];
  }
#pragma unroll
  for (int off = 32; off; off >>= 1) s += __shfl_xor(s, off);
  float mu = s * (1.0f / C_);
  float vs = 0.f;
#pragma unroll
  for (int j = 0; j < 8; j++) {
    v[j] -= mu;
    vs += v[j] * v[j];
  }
#pragma unroll
  for (int off = 32; off; off >>= 1) vs += __shfl_xor(vs, off);
  float rstd = rsqrtf(vs * (1.0f / C_) + 1e-5f);
  float4 g0 = *(const float4*)&g[c0], g1 = *(const float4*)&g[c0 + 4];
  float4 b0 = *(const float4*)&bb[c0], b1 = *(const float4*)&bb[c0 + 4];
  ushort8 r8 = *(const ushort8*)&xT[(size_t)token * C_ + c0];
  float gg[8] = {g0.x, g0.y, g0.z, g0.w, g1.x, g1.y, g1.z, g1.w};
  float bbv[8] = {b0.x, b0.y, b0.z, b0.w, b1.x, b1.y, b1.z, b1.w};
  ushort8 pk;
#pragma unroll
  for (int j = 0; j < 8; j++)
    pk[j] = f2bf(v[j] * rstd * gg[j] + bbv[j] + bf2f(r8[j]));
  *(ushort8*)&ybf[(size_t)token * C_ + c0] = pk;
}

// -------------------------------------------------------------------------
// K6: depthwise 3x3 SAME on bf16 y (token-major) -> bf16 out (+dw bias)
__global__ __launch_bounds__(256) void dwconv_kernel(
    const ushort* __restrict__ y, const float* __restrict__ w,
    const float* __restrict__ bias, ushort* __restrict__ out) {
  const int cg = threadIdx.x & 63, tg = threadIdx.x >> 6;
  const int c0 = cg * 8;
  float wreg[9][8], breg[8];
#pragma unroll
  for (int j = 0; j < 8; j++) {
    breg[j] = bias[c0 + j];
#pragma unroll
    for (int kk = 0; kk < 9; kk++) wreg[kk][j] = w[(c0 + j) * 9 + kk];
  }
  for (int i = 0; i < 4; i++) {
    int token = blockIdx.x * 16 + tg * 4 + i;
    int b = token >> 10, s = token & (HW_ - 1);
    int hh = s >> 5, ww = s & 31;
    float acc[8];
#pragma unroll
    for (int j = 0; j < 8; j++) acc[j] = breg[j];
#pragma unroll
    for (int ky = 0; ky < 3; ky++) {
      int yy = hh + ky - 1;
      if (yy < 0 || yy >= HH_) continue;
#pragma unroll
      for (int kx = 0; kx < 3; kx++) {
        int xx = ww + kx - 1;
        if (xx < 0 || xx >= WW_) continue;
        ushort8 v8 = *(const ushort8*)
            &y[((size_t)(b * HW_ + yy * 32 + xx)) * C_ + c0];
        const float* wk = wreg[ky * 3 + kx];
#pragma unroll
        for (int j = 0; j < 8; j++) acc[j] += wk[j] * bf2f(v8[j]);
      }
    }
    ushort8 pk;
#pragma unroll
    for (int j = 0; j < 8; j++) pk[j] = f2bf(acc[j]);
    *(ushort8*)&out[(size_t)token * C_ + c0] = pk;
  }
}

// -------------------------------------------------------------------------
extern "C" void kernel_launch(void* const* d_in, const int* in_sizes, int n_in,
                              void* d_out, int out_size, void* d_ws,
                              size_t ws_size, hipStream_t stream) {
  const float* x = (const float*)d_in[0];
  const float* qkv_w = (const float*)d_in[1];
  const float* proj_w = (const float*)d_in[2];
  const float* proj_b = (const float*)d_in[3];
  const float* temperature = (const float*)d_in[4];
  const float* ln_g = (const float*)d_in[5];
  const float* ln_b = (const float*)d_in[6];
  const float* pos = (const float*)d_in[7];
  const float* dw_w = (const float*)d_in[8];
  const float* dw_b = (const float*)d_in[9];
  const float* pw_w = (const float*)d_in[10];
  const float* pw_b = (const float*)d_in[11];
  float* out = (float*)d_out;

  float* ws = (float*)d_ws;
  ushort* qkv_bf = (ushort*)ws;
  ushort* t_bf = (ushort*)(ws + (size_t)6 * 1024 * 1024);
  ushort* proj_bf = (ushort*)(ws + (size_t)8 * 1024 * 1024);
  ushort* xT_bf = (ushort*)(ws + (size_t)12 * 1024 * 1024);
  ushort* wts = (ushort*)(ws + (size_t)14 * 1024 * 1024);
  ushort* qkvw_bf = wts;
  ushort* projw_bf = wts + 786432;
  ushort* pww_bf = wts + 1048576;
  float* sums = ws + (size_t)15 * 1024 * 1024;
  float* qsum = sums;
  float* ksum = sums + 4096;
  ushort* vtb = (ushort*)(ws + (size_t)16 * 1024 * 1024);

  const int M = BB_ * HW_;  // 8192 tokens

  // 1) prep: weights->bf16, t/xT transpose, zero sums
  prep_kernel<<<6176, 256, 0, stream>>>(x, pos, qkv_w, proj_w, pw_w, t_bf,
                                        xT_bf, wts, sums);
  // 2) qkv GEMM: q/k bf16 + norm-sums; V -> vt transposed
  gemm_qkv<<<dim3(C3_ / 128, M / 128), 256, 0, stream>>>(
      t_bf, qkvw_bf, qkv_bf, vtb, qsum, ksum);
  // 3) flash attention (128q/block) -> attn_out (bf16, reuses t region)
  attn_mfma_kernel<<<BB_ * NH_ * (HW_ / 128), 256, 0, stream>>>(
      qkv_bf, vtb, qsum, ksum, temperature, t_bf);
  // 4) proj GEMM (+bias, bf16 out)
  gemm_n64<1><<<dim3(C_ / 64, M / 128), 256, 0, stream>>>(
      t_bf, projw_bf, proj_b, proj_bf, nullptr, C_, C_);
  // 5) LayerNorm + residual(xT) -> y_bf (in place over xT), wave-per-token
  ln_residual_kernel<<<M / 4, 256, 0, stream>>>(proj_bf, xT_bf, ln_g, ln_b,
                                                xT_bf);
  // 6) depthwise 3x3 on bf16 y -> dw_out (bf16, reuses t region)
  dwconv_kernel<<<M / 16, 256, 0, stream>>>(xT_bf, dw_w, dw_b, t_bf);
  // 7) pointwise GEMM + pw_b + residual(y_bf), NCHW -> out
  gemm_n64<2><<<dim3(C_ / 64, M / 128), 256, 0, stream>>>(
      t_bf, pww_bf, pw_b, out, xT_bf, C_, C_);
}

// Round 10
// 208.679 us; speedup vs baseline: 1.0132x; 1.0132x over previous
//
#include <hip/hip_runtime.h>
#include <math.h>

// Problem constants
#define BB_ 8
#define C_ 512
#define C3_ 1536
#define HW_ 1024
#define NH_ 8
#define DH_ 64
#define HH_ 32
#define WW_ 32

typedef __attribute__((ext_vector_type(8))) short short8;
typedef __attribute__((ext_vector_type(4))) short short4v;
typedef __attribute__((ext_vector_type(8))) unsigned short ushort8;
typedef __attribute__((ext_vector_type(4))) unsigned short ushort4_t;
typedef __attribute__((ext_vector_type(4))) float f32x4;
typedef unsigned short ushort;

__device__ inline ushort f2bf(float f) {
  union { float f; unsigned u; } v;
  v.f = f;
  unsigned r = v.u + 0x7fffu + ((v.u >> 16) & 1u);
  return (ushort)(r >> 16);
}
__device__ inline float bf2f(ushort u) {
  union { unsigned u; float f; } v;
  v.u = ((unsigned)u) << 16;
  return v.f;
}

#define GLD16(gptr, lptr)                                                     \
  __builtin_amdgcn_global_load_lds(                                           \
      (const __attribute__((address_space(1))) unsigned int*)(gptr),          \
      (__attribute__((address_space(3))) unsigned int*)(lptr), 16, 0, 0)

// PV micro-op: D += Vt_frag(4 keys) x P_frag(4 keys), 16x16 output.
__device__ inline f32x4 pv_mfma(short4v vf, short4v pf, f32x4 acc) {
#if __has_builtin(__builtin_amdgcn_mfma_f32_16x16x16_bf16)
  return __builtin_amdgcn_mfma_f32_16x16x16_bf16(vf, pf, acc, 0, 0, 0);
#elif __has_builtin(__builtin_amdgcn_mfma_f32_16x16x16bf16_1k)
  return __builtin_amdgcn_mfma_f32_16x16x16bf16_1k(vf, pf, acc, 0, 0, 0);
#else
  short8 vf8 = {vf[0], vf[1], vf[2], vf[3], 0, 0, 0, 0};
  short8 pf8 = {pf[0], pf[1], pf[2], pf[3], 0, 0, 0, 0};
  return __builtin_amdgcn_mfma_f32_16x16x32_bf16(vf8, pf8, acc, 0, 0, 0);
#endif
}

// -------------------------------------------------------------------------
// K1 (prep): fused weight-cvt + x transpose(+pos) + qsum/ksum zeroing.
__global__ __launch_bounds__(256) void prep_kernel(
    const float* __restrict__ x, const float* __restrict__ pos,
    const float* __restrict__ qkv_w, const float* __restrict__ proj_w,
    const float* __restrict__ pw_w, ushort* __restrict__ t,
    ushort* __restrict__ xT, ushort* __restrict__ wts,
    float* __restrict__ sums) {
  const int bid = blockIdx.x;
  const int tid = threadIdx.x;
  if (bid >= 6144) {
    sums[(bid - 6144) * 256 + tid] = 0.f;
    return;
  }
  if (bid >= 1024) {
    int i = (bid - 1024) * 256 + tid;
    if (i < 786432) wts[i] = f2bf(qkv_w[i]);
    else if (i < 1048576) wts[i] = f2bf(proj_w[i - 786432]);
    else wts[i] = f2bf(pw_w[i - 1048576]);
    return;
  }
  __shared__ float tile[64][65];
  const int n0 = (bid & 15) * 64, c0 = ((bid >> 4) & 7) * 64, b = bid >> 7;
#pragma unroll
  for (int it = 0; it < 4; it++) {
    int c_l = (tid >> 4) + it * 16;
    int n_l4 = (tid & 15) * 4;
    float4 v = *(const float4*)&x[((size_t)(b * C_ + c0 + c_l)) * HW_ + n0 + n_l4];
    tile[c_l][n_l4 + 0] = v.x;
    tile[c_l][n_l4 + 1] = v.y;
    tile[c_l][n_l4 + 2] = v.z;
    tile[c_l][n_l4 + 3] = v.w;
  }
  __syncthreads();
#pragma unroll
  for (int it = 0; it < 4; it++) {
    int n_l = (tid >> 4) + it * 16;
    int c_l4 = (tid & 15) * 4;
    size_t token = (size_t)(b * HW_ + n0 + n_l);
    float4 pv = *(const float4*)&pos[(n0 + n_l) * C_ + c0 + c_l4];
    float xv0 = tile[c_l4 + 0][n_l], xv1 = tile[c_l4 + 1][n_l];
    float xv2 = tile[c_l4 + 2][n_l], xv3 = tile[c_l4 + 3][n_l];
    ushort4_t tb = {f2bf(xv0 + pv.x), f2bf(xv1 + pv.y), f2bf(xv2 + pv.z),
                    f2bf(xv3 + pv.w)};
    ushort4_t xb = {f2bf(xv0), f2bf(xv1), f2bf(xv2), f2bf(xv3)};
    *(ushort4_t*)&t[token * C_ + c0 + c_l4] = tb;
    *(ushort4_t*)&xT[token * C_ + c0 + c_l4] = xb;
  }
}

// -------------------------------------------------------------------------
// K2: qkv GEMM (m97 structure, 128x128). Epilogue: q/k bf16 + norm-sums;
// V -> transposed bf16 store into vt[bh*64+d][n].
__global__ __launch_bounds__(256) void gemm_qkv(
    const ushort* __restrict__ A, const ushort* __restrict__ Wm,
    ushort* __restrict__ out, ushort* __restrict__ vt,
    float* __restrict__ qsum, float* __restrict__ ksum) {
  const int N = C3_, K = C_;
  __shared__ alignas(16) ushort As[128 * 32];
  __shared__ alignas(16) ushort Bs[128 * 32];
  const int bn = blockIdx.x * 128, bm = blockIdx.y * 128;
  const int tid = threadIdx.x;
  const int w = tid >> 6, lane = tid & 63;
  const int wm = 64 * (w & 1), wn = 64 * (w >> 1);
  const int l15 = lane & 15, lq = lane >> 4;

  f32x4 acc[4][4];
#pragma unroll
  for (int i = 0; i < 4; i++)
#pragma unroll
    for (int j = 0; j < 4; j++) acc[i][j] = (f32x4){0.f, 0.f, 0.f, 0.f};

  const int srr = lane >> 2, sq1 = lane & 3;

  for (int k0 = 0; k0 < K; k0 += 32) {
    __syncthreads();
#pragma unroll
    for (int j = 0; j < 2; j++) {
      int r = 32 * w + 16 * j + srr;
      int q = (sq1 - (r >> 1)) & 3;
      GLD16(A + (size_t)(bm + r) * K + k0 + q * 8, &As[(32 * w + 16 * j) * 32]);
      GLD16(Wm + (size_t)(bn + r) * K + k0 + q * 8, &Bs[(32 * w + 16 * j) * 32]);
    }
    __syncthreads();
    short8 af[4], bf[4];
#pragma unroll
    for (int nt = 0; nt < 4; nt++) {
      int r = wm + nt * 16 + l15;
      af[nt] = *(const short8*)&As[r * 32 + (((lq + (r >> 1)) & 3) * 8)];
      int c = wn + nt * 16 + l15;
      bf[nt] = *(const short8*)&Bs[c * 32 + (((lq + (c >> 1)) & 3) * 8)];
    }
#pragma unroll
    for (int i = 0; i < 4; i++)
#pragma unroll
      for (int j = 0; j < 4; j++)
        acc[i][j] = __builtin_amdgcn_mfma_f32_16x16x32_bf16(af[i], bf[j],
                                                            acc[i][j], 0, 0, 0);
  }

  const int b = bm >> 10;
  if (bn < 1024) {
#pragma unroll
    for (int j = 0; j < 4; j++) {
      int c = bn + wn + j * 16 + l15;
      float ss = 0.f;
#pragma unroll
      for (int i = 0; i < 4; i++) {
#pragma unroll
        for (int r = 0; r < 4; r++) {
          int m = bm + wm + i * 16 + lq * 4 + r;
          float v = acc[i][j][r];
          ss += v * v;
          out[(size_t)m * N + c] = f2bf(v);
        }
      }
      ss += __shfl_xor(ss, 16);
      ss += __shfl_xor(ss, 32);
      if (lq == 0) {
        if (c < 512) atomicAdd(&qsum[b * 512 + c], ss);
        else atomicAdd(&ksum[b * 512 + c - 512], ss);
      }
    }
  } else {
#pragma unroll
    for (int j = 0; j < 4; j++) {
      int c = bn + wn + j * 16 + l15;
      int hd = c - 1024;
      ushort* vrow = vt + ((size_t)(b * 512 + hd)) * HW_;
#pragma unroll
      for (int i = 0; i < 4; i++) {
        int n0 = (bm & 1023) + wm + i * 16 + lq * 4;
        ushort4_t pv = {f2bf(acc[i][j][0]), f2bf(acc[i][j][1]),
                        f2bf(acc[i][j][2]), f2bf(acc[i][j][3])};
        *(ushort4_t*)&vrow[n0] = pv;
      }
    }
  }
}

// -------------------------------------------------------------------------
// bf16 MFMA GEMM 128x64 tiles. EPI 1: bf16 +bias token-major.
// EPI 2: f32 +bias +resid(bf16), NCHW store.
template <int EPI>
__global__ __launch_bounds__(256) void gemm_n64(
    const ushort* __restrict__ A, const ushort* __restrict__ Wm,
    const float* __restrict__ bias, void* __restrict__ outv,
    const ushort* __restrict__ resid, int N, int K) {
  __shared__ alignas(16) ushort As[128 * 32];
  __shared__ alignas(16) ushort Bs[64 * 32];
  const int bn = blockIdx.x * 64, bm = blockIdx.y * 128;
  const int tid = threadIdx.x;
  const int w = tid >> 6, lane = tid & 63;
  const int wm = 64 * (w & 1), wn = 32 * (w >> 1);
  const int l15 = lane & 15, lq = lane >> 4;

  f32x4 acc[4][2];
#pragma unroll
  for (int i = 0; i < 4; i++)
#pragma unroll
    for (int j = 0; j < 2; j++) acc[i][j] = (f32x4){0.f, 0.f, 0.f, 0.f};

  const int srr = lane >> 2, sq1 = lane & 3;

  for (int k0 = 0; k0 < K; k0 += 32) {
    __syncthreads();
#pragma unroll
    for (int j = 0; j < 2; j++) {
      int r = 32 * w + 16 * j + srr;
      int q = (sq1 - (r >> 1)) & 3;
      GLD16(A + (size_t)(bm + r) * K + k0 + q * 8, &As[(32 * w + 16 * j) * 32]);
    }
    {
      int r = 16 * w + srr;
      int q = (sq1 - (r >> 1)) & 3;
      GLD16(Wm + (size_t)(bn + r) * K + k0 + q * 8, &Bs[(16 * w) * 32]);
    }
    __syncthreads();
    short8 af[4], bf[2];
#pragma unroll
    for (int nt = 0; nt < 4; nt++) {
      int r = wm + nt * 16 + l15;
      af[nt] = *(const short8*)&As[r * 32 + (((lq + (r >> 1)) & 3) * 8)];
    }
#pragma unroll
    for (int j = 0; j < 2; j++) {
      int c = wn + j * 16 + l15;
      bf[j] = *(const short8*)&Bs[c * 32 + (((lq + (c >> 1)) & 3) * 8)];
    }
#pragma unroll
    for (int i = 0; i < 4; i++)
#pragma unroll
      for (int j = 0; j < 2; j++)
        acc[i][j] = __builtin_amdgcn_mfma_f32_16x16x32_bf16(af[i], bf[j],
                                                            acc[i][j], 0, 0, 0);
  }

#pragma unroll
  for (int i = 0; i < 4; i++) {
#pragma unroll
    for (int j = 0; j < 2; j++) {
      int c = bn + wn + j * 16 + l15;
      float bv = bias[c];
#pragma unroll
      for (int r = 0; r < 4; r++) {
        int m = bm + wm + i * 16 + lq * 4 + r;
        float v = acc[i][j][r] + bv;
        if (EPI == 1) {
          ((ushort*)outv)[(size_t)m * N + c] = f2bf(v);
        } else {
          int b = m >> 10, s = m & (HW_ - 1);
          ((float*)outv)[((size_t)(b * C_ + c)) * HW_ + s] =
              v + bf2f(resid[(size_t)m * C_ + c]);
        }
      }
    }
  }
}

// -------------------------------------------------------------------------
// K3: MFMA flash attention, 64 queries/block (grid 1024, 4 blocks/CU).
// Block index is bh-minor: bh = blockIdx & 63 -> all 16 q-tiles of a
// (b,h) land on the SAME XCD (round-robin dispatch), so K/V stay
// L2-resident (8 bh/XCD x 256 KB = 2 MB < 4 MB L2).
// Double-buffered direct-to-LDS staging, one barrier per K-tile.
__global__ __launch_bounds__(256) void attn_mfma_kernel(
    const ushort* __restrict__ qkv, const ushort* __restrict__ vt,
    const float* __restrict__ qsum, const float* __restrict__ ksum,
    const float* __restrict__ temp, ushort* __restrict__ o) {
  __shared__ alignas(16) ushort Ks[2][64 * 64];   // [key][d], chunk-swizzled
  __shared__ alignas(16) ushort Vts[2][64 * 64];  // [d][key], chunk-swizzled
  __shared__ float sc_lds[64];

  const int tid = threadIdx.x;
  const int w = tid >> 6, lane = tid & 63;
  const int quad = lane >> 4, lcol = lane & 15;
  const int bh = blockIdx.x & 63;   // XCD-locality: bh determines XCD
  const int qt = blockIdx.x >> 6;
  const int b = bh >> 3, h = bh & 7;
  const int q0 = qt * 64;

  if (tid < 64) {
    float qs = qsum[b * 512 + h * 64 + tid];
    float ks = ksum[b * 512 + h * 64 + tid];
    float iq = 1.0f / fmaxf(sqrtf(qs), 1e-12f);
    float ik = 1.0f / fmaxf(sqrtf(ks), 1e-12f);
    sc_lds[tid] = iq * ik * temp[h];
  }

  const ushort* kg = qkv + (size_t)b * HW_ * C3_ + C_ + h * 64;
  const ushort* vg = vt + (size_t)(bh * 64) * HW_;

  // staging: 256 threads x 2 iters cover 64 rows x 8 chunks (of 8 bf16)
  const int srow0 = tid >> 3;  // 0..31
  const int sc = tid & 7;

  // prologue: stage tile 0 into buffer 0
#pragma unroll
  for (int it = 0; it < 2; it++) {
    int row = srow0 + it * 32;
    int scg = sc ^ (row & 7);
    GLD16(kg + (size_t)row * C3_ + scg * 8, &Ks[0][w * 512 + it * 2048]);
    GLD16(vg + (size_t)row * HW_ + scg * 8, &Vts[0][w * 512 + it * 2048]);
  }
  __syncthreads();

  // Q fragment (B-operand of S^T = K·Q^T), scales folded in.
  short8 qf[2];
  {
    const int m = q0 + w * 16 + lcol;
    const ushort* qrow = qkv + ((size_t)(b * HW_ + m)) * C3_ + h * 64;
#pragma unroll
    for (int kc = 0; kc < 2; kc++) {
      union { short8 v; ushort u[8]; } pk;
#pragma unroll
      for (int j = 0; j < 8; j++) {
        int d = kc * 32 + quad * 8 + j;
        pk.u[j] = f2bf(bf2f(qrow[d]) * sc_lds[d]);
      }
      qf[kc] = pk.v;
    }
  }

  f32x4 ot[4];
#pragma unroll
  for (int dt = 0; dt < 4; dt++) ot[dt] = (f32x4){0.f, 0.f, 0.f, 0.f};
  float lsum = 0.f;

  for (int kt = 0; kt < 16; kt++) {
    if (kt > 0) __syncthreads();  // drains GLD(kt) + prior buffer reads
    const int cur = kt & 1;
    if (kt + 1 < 16) {
      const int nxt = cur ^ 1;
#pragma unroll
      for (int it = 0; it < 2; it++) {
        int row = srow0 + it * 32;
        int scg = sc ^ (row & 7);
        GLD16(kg + (size_t)((kt + 1) * 64 + row) * C3_ + scg * 8,
              &Ks[nxt][w * 512 + it * 2048]);
        GLD16(vg + (size_t)row * HW_ + (kt + 1) * 64 + scg * 8,
              &Vts[nxt][w * 512 + it * 2048]);
      }
    }

    // S^T = K·Q^T
    f32x4 sfr[4];
#pragma unroll
    for (int nt = 0; nt < 4; nt++) sfr[nt] = (f32x4){0.f, 0.f, 0.f, 0.f};
#pragma unroll
    for (int kc = 0; kc < 2; kc++) {
#pragma unroll
      for (int nt = 0; nt < 4; nt++) {
        int row = nt * 16 + lcol;
        short8 kf = *(const short8*)
            &Ks[cur][row * 64 + (((kc * 4 + quad) ^ (row & 7)) * 8)];
        sfr[nt] =
            __builtin_amdgcn_mfma_f32_16x16x32_bf16(kf, qf[kc], sfr[nt], 0, 0, 0);
      }
    }

    // exp (fixed max: scores bounded ~0.07) + per-lane sum + pack P
    short4v pk[4];
#pragma unroll
    for (int nt = 0; nt < 4; nt++) {
      float f0 = __expf(sfr[nt][0]);
      float f1 = __expf(sfr[nt][1]);
      float f2 = __expf(sfr[nt][2]);
      float f3 = __expf(sfr[nt][3]);
      lsum += f0 + f1 + f2 + f3;
      pk[nt] = (short4v){(short)f2bf(f0), (short)f2bf(f1), (short)f2bf(f2),
                         (short)f2bf(f3)};
    }

    // O^T += V^T · P^T  (x16 MFMAs, P from registers)
#pragma unroll
    for (int nt = 0; nt < 4; nt++) {
      int key = nt * 16 + quad * 4;
#pragma unroll
      for (int dt = 0; dt < 4; dt++) {
        int d = dt * 16 + lcol;
        short4v vf = *(const short4v*)
            &Vts[cur][d * 64 + (((key >> 3) ^ (d & 7)) * 8) + (key & 7)];
        ot[dt] = pv_mfma(vf, pk[nt], ot[dt]);
      }
    }
  }

  lsum += __shfl_xor(lsum, 16);
  lsum += __shfl_xor(lsum, 32);
  const float inv = 1.0f / lsum;

  const int m = q0 + w * 16 + lcol;
  ushort* orow = o + ((size_t)(b * HW_ + m)) * C_ + h * 64;
#pragma unroll
  for (int dt = 0; dt < 4; dt++) {
    ushort4_t pkb = {f2bf(ot[dt][0] * inv), f2bf(ot[dt][1] * inv),
                     f2bf(ot[dt][2] * inv), f2bf(ot[dt][3] * inv)};
    *(ushort4_t*)&orow[dt * 16 + quad * 4] = pkb;
  }
}

// -------------------------------------------------------------------------
// K5: LayerNorm, wave-per-token (no LDS, no barriers). bf16 in/out,
// residual xT bf16; writes y_bf in place over xT.
__global__ __launch_bounds__(256) void ln_residual_kernel(
    const ushort* __restrict__ po, const ushort* xT,
    const float* __restrict__ g, const float* __restrict__ bb, ushort* ybf) {
  const int wv = threadIdx.x >> 6, lane = threadIdx.x & 63;
  const int token = blockIdx.x * 4 + wv;
  const int c0 = lane * 8;
  ushort8 p8 = *(const ushort8*)&po[(size_t)token * C_ + c0];
  float v[8];
  float s = 0.f;
#pragma unroll
  for (int j = 0; j < 8; j++) {
    v[j] = bf2f(p8[j]);
    s += v[j];
  }
#pragma unroll
  for (int off = 32; off; off >>= 1) s += __shfl_xor(s, off);
  float mu = s * (1.0f / C_);
  float vs = 0.f;
#pragma unroll
  for (int j = 0; j < 8; j++) {
    v[j] -= mu;
    vs += v[j] * v[j];
  }
#pragma unroll
  for (int off = 32; off; off >>= 1) vs += __shfl_xor(vs, off);
  float rstd = rsqrtf(vs * (1.0f / C_) + 1e-5f);
  float4 g0 = *(const float4*)&g[c0], g1 = *(const float4*)&g[c0 + 4];
  float4 b0 = *(const float4*)&bb[c0], b1 = *(const float4*)&bb[c0 + 4];
  ushort8 r8 = *(const ushort8*)&xT[(size_t)token * C_ + c0];
  float gg[8] = {g0.x, g0.y, g0.z, g0.w, g1.x, g1.y, g1.z, g1.w};
  float bbv[8] = {b0.x, b0.y, b0.z, b0.w, b1.x, b1.y, b1.z, b1.w};
  ushort8 pk;
#pragma unroll
  for (int j = 0; j < 8; j++)
    pk[j] = f2bf(v[j] * rstd * gg[j] + bbv[j] + bf2f(r8[j]));
  *(ushort8*)&ybf[(size_t)token * C_ + c0] = pk;
}

// -------------------------------------------------------------------------
// K6: depthwise 3x3 SAME on bf16 y (token-major) -> bf16 out (+dw bias)
__global__ __launch_bounds__(256) void dwconv_kernel(
    const ushort* __restrict__ y, const float* __restrict__ w,
    const float* __restrict__ bias, ushort* __restrict__ out) {
  const int cg = threadIdx.x & 63, tg = threadIdx.x >> 6;
  const int c0 = cg * 8;
  float wreg[9][8], breg[8];
#pragma unroll
  for (int j = 0; j < 8; j++) {
    breg[j] = bias[c0 + j];
#pragma unroll
    for (int kk = 0; kk < 9; kk++) wreg[kk][j] = w[(c0 + j) * 9 + kk];
  }
  for (int i = 0; i < 4; i++) {
    int token = blockIdx.x * 16 + tg * 4 + i;
    int b = token >> 10, s = token & (HW_ - 1);
    int hh = s >> 5, ww = s & 31;
    float acc[8];
#pragma unroll
    for (int j = 0; j < 8; j++) acc[j] = breg[j];
#pragma unroll
    for (int ky = 0; ky < 3; ky++) {
      int yy = hh + ky - 1;
      if (yy < 0 || yy >= HH_) continue;
#pragma unroll
      for (int kx = 0; kx < 3; kx++) {
        int xx = ww + kx - 1;
        if (xx < 0 || xx >= WW_) continue;
        ushort8 v8 = *(const ushort8*)
            &y[((size_t)(b * HW_ + yy * 32 + xx)) * C_ + c0];
        const float* wk = wreg[ky * 3 + kx];
#pragma unroll
        for (int j = 0; j < 8; j++) acc[j] += wk[j] * bf2f(v8[j]);
      }
    }
    ushort8 pk;
#pragma unroll
    for (int j = 0; j < 8; j++) pk[j] = f2bf(acc[j]);
    *(ushort8*)&out[(size_t)token * C_ + c0] = pk;
  }
}

// -------------------------------------------------------------------------
extern "C" void kernel_launch(void* const* d_in, const int* in_sizes, int n_in,
                              void* d_out, int out_size, void* d_ws,
                              size_t ws_size, hipStream_t stream) {
  const float* x = (const float*)d_in[0];
  const float* qkv_w = (const float*)d_in[1];
  const float* proj_w = (const float*)d_in[2];
  const float* proj_b = (const float*)d_in[3];
  const float* temperature = (const float*)d_in[4];
  const float* ln_g = (const float*)d_in[5];
  const float* ln_b = (const float*)d_in[6];
  const float* pos = (const float*)d_in[7];
  const float* dw_w = (const float*)d_in[8];
  const float* dw_b = (const float*)d_in[9];
  const float* pw_w = (const float*)d_in[10];
  const float* pw_b = (const float*)d_in[11];
  float* out = (float*)d_out;

  float* ws = (float*)d_ws;
  ushort* qkv_bf = (ushort*)ws;
  ushort* t_bf = (ushort*)(ws + (size_t)6 * 1024 * 1024);
  ushort* proj_bf = (ushort*)(ws + (size_t)8 * 1024 * 1024);
  ushort* xT_bf = (ushort*)(ws + (size_t)12 * 1024 * 1024);
  ushort* wts = (ushort*)(ws + (size_t)14 * 1024 * 1024);
  ushort* qkvw_bf = wts;
  ushort* projw_bf = wts + 786432;
  ushort* pww_bf = wts + 1048576;
  float* sums = ws + (size_t)15 * 1024 * 1024;
  float* qsum = sums;
  float* ksum = sums + 4096;
  ushort* vtb = (ushort*)(ws + (size_t)16 * 1024 * 1024);

  const int M = BB_ * HW_;  // 8192 tokens

  // 1) prep: weights->bf16, t/xT transpose, zero sums
  prep_kernel<<<6176, 256, 0, stream>>>(x, pos, qkv_w, proj_w, pw_w, t_bf,
                                        xT_bf, wts, sums);
  // 2) qkv GEMM: q/k bf16 + norm-sums; V -> vt transposed
  gemm_qkv<<<dim3(C3_ / 128, M / 128), 256, 0, stream>>>(
      t_bf, qkvw_bf, qkv_bf, vtb, qsum, ksum);
  // 3) flash attention (64q/block, bh-minor XCD-local order) -> attn_out
  attn_mfma_kernel<<<BB_ * NH_ * (HW_ / 64), 256, 0, stream>>>(
      qkv_bf, vtb, qsum, ksum, temperature, t_bf);
  // 4) proj GEMM (+bias, bf16 out)
  gemm_n64<1><<<dim3(C_ / 64, M / 128), 256, 0, stream>>>(
      t_bf, projw_bf, proj_b, proj_bf, nullptr, C_, C_);
  // 5) LayerNorm + residual(xT) -> y_bf (in place over xT), wave-per-token
  ln_residual_kernel<<<M / 4, 256, 0, stream>>>(proj_bf, xT_bf, ln_g, ln_b,
                                                xT_bf);
  // 6) depthwise 3x3 on bf16 y -> dw_out (bf16, reuses t region)
  dwconv_kernel<<<M / 16, 256, 0, stream>>>(xT_bf, dw_w, dw_b, t_bf);
  // 7) pointwise GEMM + pw_b + residual(y_bf), NCHW -> out
  gemm_n64<2><<<dim3(C_ / 64, M / 128), 256, 0, stream>>>(
      t_bf, pww_bf, pw_b, out, xT_bf, C_, C_);
}

// Round 11
// 204.775 us; speedup vs baseline: 1.0325x; 1.0191x over previous
//
#include <hip/hip_runtime.h>
#include <math.h>

// Problem constants
#define BB_ 8
#define C_ 512
#define C3_ 1536
#define HW_ 1024
#define NH_ 8
#define DH_ 64
#define HH_ 32
#define WW_ 32

typedef __attribute__((ext_vector_type(8))) short short8;
typedef __attribute__((ext_vector_type(4))) short short4v;
typedef __attribute__((ext_vector_type(8))) unsigned short ushort8;
typedef __attribute__((ext_vector_type(4))) unsigned short ushort4_t;
typedef __attribute__((ext_vector_type(4))) float f32x4;
typedef unsigned short ushort;

__device__ inline ushort f2bf(float f) {
  union { float f; unsigned u; } v;
  v.f = f;
  unsigned r = v.u + 0x7fffu + ((v.u >> 16) & 1u);
  return (ushort)(r >> 16);
}
__device__ inline float bf2f(ushort u) {
  union { unsigned u; float f; } v;
  v.u = ((unsigned)u) << 16;
  return v.f;
}

#define GLD16(gptr, lptr)                                                     \
  __builtin_amdgcn_global_load_lds(                                           \
      (const __attribute__((address_space(1))) unsigned int*)(gptr),          \
      (__attribute__((address_space(3))) unsigned int*)(lptr), 16, 0, 0)

// PV micro-op: D += Vt_frag(4 keys) x P_frag(4 keys), 16x16 output.
__device__ inline f32x4 pv_mfma(short4v vf, short4v pf, f32x4 acc) {
#if __has_builtin(__builtin_amdgcn_mfma_f32_16x16x16_bf16)
  return __builtin_amdgcn_mfma_f32_16x16x16_bf16(vf, pf, acc, 0, 0, 0);
#elif __has_builtin(__builtin_amdgcn_mfma_f32_16x16x16bf16_1k)
  return __builtin_amdgcn_mfma_f32_16x16x16bf16_1k(vf, pf, acc, 0, 0, 0);
#else
  short8 vf8 = {vf[0], vf[1], vf[2], vf[3], 0, 0, 0, 0};
  short8 pf8 = {pf[0], pf[1], pf[2], pf[3], 0, 0, 0, 0};
  return __builtin_amdgcn_mfma_f32_16x16x32_bf16(vf8, pf8, acc, 0, 0, 0);
#endif
}

// -------------------------------------------------------------------------
// K1 (prep): fused weight-cvt + x transpose(+pos) + qsum/ksum zeroing.
__global__ __launch_bounds__(256) void prep_kernel(
    const float* __restrict__ x, const float* __restrict__ pos,
    const float* __restrict__ qkv_w, const float* __restrict__ proj_w,
    const float* __restrict__ pw_w, ushort* __restrict__ t,
    ushort* __restrict__ xT, ushort* __restrict__ wts,
    float* __restrict__ sums) {
  const int bid = blockIdx.x;
  const int tid = threadIdx.x;
  if (bid >= 6144) {
    sums[(bid - 6144) * 256 + tid] = 0.f;
    return;
  }
  if (bid >= 1024) {
    int i = (bid - 1024) * 256 + tid;
    if (i < 786432) wts[i] = f2bf(qkv_w[i]);
    else if (i < 1048576) wts[i] = f2bf(proj_w[i - 786432]);
    else wts[i] = f2bf(pw_w[i - 1048576]);
    return;
  }
  __shared__ float tile[64][65];
  const int n0 = (bid & 15) * 64, c0 = ((bid >> 4) & 7) * 64, b = bid >> 7;
#pragma unroll
  for (int it = 0; it < 4; it++) {
    int c_l = (tid >> 4) + it * 16;
    int n_l4 = (tid & 15) * 4;
    float4 v = *(const float4*)&x[((size_t)(b * C_ + c0 + c_l)) * HW_ + n0 + n_l4];
    tile[c_l][n_l4 + 0] = v.x;
    tile[c_l][n_l4 + 1] = v.y;
    tile[c_l][n_l4 + 2] = v.z;
    tile[c_l][n_l4 + 3] = v.w;
  }
  __syncthreads();
#pragma unroll
  for (int it = 0; it < 4; it++) {
    int n_l = (tid >> 4) + it * 16;
    int c_l4 = (tid & 15) * 4;
    size_t token = (size_t)(b * HW_ + n0 + n_l);
    float4 pv = *(const float4*)&pos[(n0 + n_l) * C_ + c0 + c_l4];
    float xv0 = tile[c_l4 + 0][n_l], xv1 = tile[c_l4 + 1][n_l];
    float xv2 = tile[c_l4 + 2][n_l], xv3 = tile[c_l4 + 3][n_l];
    ushort4_t tb = {f2bf(xv0 + pv.x), f2bf(xv1 + pv.y), f2bf(xv2 + pv.z),
                    f2bf(xv3 + pv.w)};
    ushort4_t xb = {f2bf(xv0), f2bf(xv1), f2bf(xv2), f2bf(xv3)};
    *(ushort4_t*)&t[token * C_ + c0 + c_l4] = tb;
    *(ushort4_t*)&xT[token * C_ + c0 + c_l4] = xb;
  }
}

// -------------------------------------------------------------------------
// K2: qkv GEMM (m97 structure, 128x128). Epilogue: q/k bf16 + norm-sums;
// V -> transposed bf16 store into vt[bh*64+d][n].
__global__ __launch_bounds__(256) void gemm_qkv(
    const ushort* __restrict__ A, const ushort* __restrict__ Wm,
    ushort* __restrict__ out, ushort* __restrict__ vt,
    float* __restrict__ qsum, float* __restrict__ ksum) {
  const int N = C3_, K = C_;
  __shared__ alignas(16) ushort As[128 * 32];
  __shared__ alignas(16) ushort Bs[128 * 32];
  const int bn = blockIdx.x * 128, bm = blockIdx.y * 128;
  const int tid = threadIdx.x;
  const int w = tid >> 6, lane = tid & 63;
  const int wm = 64 * (w & 1), wn = 64 * (w >> 1);
  const int l15 = lane & 15, lq = lane >> 4;

  f32x4 acc[4][4];
#pragma unroll
  for (int i = 0; i < 4; i++)
#pragma unroll
    for (int j = 0; j < 4; j++) acc[i][j] = (f32x4){0.f, 0.f, 0.f, 0.f};

  const int srr = lane >> 2, sq1 = lane & 3;

  for (int k0 = 0; k0 < K; k0 += 32) {
    __syncthreads();
#pragma unroll
    for (int j = 0; j < 2; j++) {
      int r = 32 * w + 16 * j + srr;
      int q = (sq1 - (r >> 1)) & 3;
      GLD16(A + (size_t)(bm + r) * K + k0 + q * 8, &As[(32 * w + 16 * j) * 32]);
      GLD16(Wm + (size_t)(bn + r) * K + k0 + q * 8, &Bs[(32 * w + 16 * j) * 32]);
    }
    __syncthreads();
    short8 af[4], bf[4];
#pragma unroll
    for (int nt = 0; nt < 4; nt++) {
      int r = wm + nt * 16 + l15;
      af[nt] = *(const short8*)&As[r * 32 + (((lq + (r >> 1)) & 3) * 8)];
      int c = wn + nt * 16 + l15;
      bf[nt] = *(const short8*)&Bs[c * 32 + (((lq + (c >> 1)) & 3) * 8)];
    }
#pragma unroll
    for (int i = 0; i < 4; i++)
#pragma unroll
      for (int j = 0; j < 4; j++)
        acc[i][j] = __builtin_amdgcn_mfma_f32_16x16x32_bf16(af[i], bf[j],
                                                            acc[i][j], 0, 0, 0);
  }

  const int b = bm >> 10;
  if (bn < 1024) {
#pragma unroll
    for (int j = 0; j < 4; j++) {
      int c = bn + wn + j * 16 + l15;
      float ss = 0.f;
#pragma unroll
      for (int i = 0; i < 4; i++) {
#pragma unroll
        for (int r = 0; r < 4; r++) {
          int m = bm + wm + i * 16 + lq * 4 + r;
          float v = acc[i][j][r];
          ss += v * v;
          out[(size_t)m * N + c] = f2bf(v);
        }
      }
      ss += __shfl_xor(ss, 16);
      ss += __shfl_xor(ss, 32);
      if (lq == 0) {
        if (c < 512) atomicAdd(&qsum[b * 512 + c], ss);
        else atomicAdd(&ksum[b * 512 + c - 512], ss);
      }
    }
  } else {
#pragma unroll
    for (int j = 0; j < 4; j++) {
      int c = bn + wn + j * 16 + l15;
      int hd = c - 1024;
      ushort* vrow = vt + ((size_t)(b * 512 + hd)) * HW_;
#pragma unroll
      for (int i = 0; i < 4; i++) {
        int n0 = (bm & 1023) + wm + i * 16 + lq * 4;
        ushort4_t pv = {f2bf(acc[i][j][0]), f2bf(acc[i][j][1]),
                        f2bf(acc[i][j][2]), f2bf(acc[i][j][3])};
        *(ushort4_t*)&vrow[n0] = pv;
      }
    }
  }
}

// -------------------------------------------------------------------------
// bf16 MFMA GEMM 128x64 tiles. EPI 1: bf16 +bias token-major.
// EPI 2: f32 +bias +resid(bf16), NCHW store.
template <int EPI>
__global__ __launch_bounds__(256) void gemm_n64(
    const ushort* __restrict__ A, const ushort* __restrict__ Wm,
    const float* __restrict__ bias, void* __restrict__ outv,
    const ushort* __restrict__ resid, int N, int K) {
  __shared__ alignas(16) ushort As[128 * 32];
  __shared__ alignas(16) ushort Bs[64 * 32];
  const int bn = blockIdx.x * 64, bm = blockIdx.y * 128;
  const int tid = threadIdx.x;
  const int w = tid >> 6, lane = tid & 63;
  const int wm = 64 * (w & 1), wn = 32 * (w >> 1);
  const int l15 = lane & 15, lq = lane >> 4;

  f32x4 acc[4][2];
#pragma unroll
  for (int i = 0; i < 4; i++)
#pragma unroll
    for (int j = 0; j < 2; j++) acc[i][j] = (f32x4){0.f, 0.f, 0.f, 0.f};

  const int srr = lane >> 2, sq1 = lane & 3;

  for (int k0 = 0; k0 < K; k0 += 32) {
    __syncthreads();
#pragma unroll
    for (int j = 0; j < 2; j++) {
      int r = 32 * w + 16 * j + srr;
      int q = (sq1 - (r >> 1)) & 3;
      GLD16(A + (size_t)(bm + r) * K + k0 + q * 8, &As[(32 * w + 16 * j) * 32]);
    }
    {
      int r = 16 * w + srr;
      int q = (sq1 - (r >> 1)) & 3;
      GLD16(Wm + (size_t)(bn + r) * K + k0 + q * 8, &Bs[(16 * w) * 32]);
    }
    __syncthreads();
    short8 af[4], bf[2];
#pragma unroll
    for (int nt = 0; nt < 4; nt++) {
      int r = wm + nt * 16 + l15;
      af[nt] = *(const short8*)&As[r * 32 + (((lq + (r >> 1)) & 3) * 8)];
    }
#pragma unroll
    for (int j = 0; j < 2; j++) {
      int c = wn + j * 16 + l15;
      bf[j] = *(const short8*)&Bs[c * 32 + (((lq + (c >> 1)) & 3) * 8)];
    }
#pragma unroll
    for (int i = 0; i < 4; i++)
#pragma unroll
      for (int j = 0; j < 2; j++)
        acc[i][j] = __builtin_amdgcn_mfma_f32_16x16x32_bf16(af[i], bf[j],
                                                            acc[i][j], 0, 0, 0);
  }

#pragma unroll
  for (int i = 0; i < 4; i++) {
#pragma unroll
    for (int j = 0; j < 2; j++) {
      int c = bn + wn + j * 16 + l15;
      float bv = bias[c];
#pragma unroll
      for (int r = 0; r < 4; r++) {
        int m = bm + wm + i * 16 + lq * 4 + r;
        float v = acc[i][j][r] + bv;
        if (EPI == 1) {
          ((ushort*)outv)[(size_t)m * N + c] = f2bf(v);
        } else {
          int b = m >> 10, s = m & (HW_ - 1);
          ((float*)outv)[((size_t)(b * C_ + c)) * HW_ + s] =
              v + bf2f(resid[(size_t)m * C_ + c]);
        }
      }
    }
  }
}

// -------------------------------------------------------------------------
// K3: MFMA flash attention, 32 queries/wave (128q/block, grid 512) with
// bh-MINOR block index: bh = blk & 63 -> all 8 q-tiles of a (b,h) land on
// the same XCD (round-robin dispatch), K/V stay L2-resident. Each K/Vt
// fragment read feeds TWO MFMAs (q-group reuse) — halves LDS reads.
// Double-buffered direct-to-LDS staging, one barrier per K-tile.
__global__ __launch_bounds__(256) void attn_mfma_kernel(
    const ushort* __restrict__ qkv, const ushort* __restrict__ vt,
    const float* __restrict__ qsum, const float* __restrict__ ksum,
    const float* __restrict__ temp, ushort* __restrict__ o) {
  __shared__ alignas(16) ushort Ks[2][64 * 64];   // [key][d], chunk-swizzled
  __shared__ alignas(16) ushort Vts[2][64 * 64];  // [d][key], chunk-swizzled
  __shared__ float sc_lds[64];

  const int tid = threadIdx.x;
  const int w = tid >> 6, lane = tid & 63;
  const int quad = lane >> 4, lcol = lane & 15;
  const int bh = blockIdx.x & 63;   // XCD-locality: bh determines XCD
  const int qt = blockIdx.x >> 6;   // 0..7
  const int b = bh >> 3, h = bh & 7;
  const int q0 = qt * 128;

  if (tid < 64) {
    float qs = qsum[b * 512 + h * 64 + tid];
    float ks = ksum[b * 512 + h * 64 + tid];
    float iq = 1.0f / fmaxf(sqrtf(qs), 1e-12f);
    float ik = 1.0f / fmaxf(sqrtf(ks), 1e-12f);
    sc_lds[tid] = iq * ik * temp[h];
  }

  const ushort* kg = qkv + (size_t)b * HW_ * C3_ + C_ + h * 64;
  const ushort* vg = vt + (size_t)(bh * 64) * HW_;

  // staging: 256 threads x 2 iters cover 64 rows x 8 chunks (of 8 bf16)
  const int srow0 = tid >> 3;  // 0..31
  const int sc = tid & 7;

  // prologue: stage tile 0 into buffer 0
#pragma unroll
  for (int it = 0; it < 2; it++) {
    int row = srow0 + it * 32;
    int scg = sc ^ (row & 7);
    GLD16(kg + (size_t)row * C3_ + scg * 8, &Ks[0][w * 512 + it * 2048]);
    GLD16(vg + (size_t)row * HW_ + scg * 8, &Vts[0][w * 512 + it * 2048]);
  }
  __syncthreads();

  // Q fragments for both q-groups (B-operand of S^T = K·Q^T), scales folded.
  short8 qf[2][2];
#pragma unroll
  for (int qg = 0; qg < 2; qg++) {
    const int m = q0 + w * 32 + qg * 16 + lcol;
    const ushort* qrow = qkv + ((size_t)(b * HW_ + m)) * C3_ + h * 64;
#pragma unroll
    for (int kc = 0; kc < 2; kc++) {
      union { short8 v; ushort u[8]; } pk;
#pragma unroll
      for (int j = 0; j < 8; j++) {
        int d = kc * 32 + quad * 8 + j;
        pk.u[j] = f2bf(bf2f(qrow[d]) * sc_lds[d]);
      }
      qf[qg][kc] = pk.v;
    }
  }

  f32x4 ot[2][4];
#pragma unroll
  for (int qg = 0; qg < 2; qg++)
#pragma unroll
    for (int dt = 0; dt < 4; dt++) ot[qg][dt] = (f32x4){0.f, 0.f, 0.f, 0.f};
  float lsum[2] = {0.f, 0.f};

  for (int kt = 0; kt < 16; kt++) {
    if (kt > 0) __syncthreads();  // drains GLD(kt) + prior buffer reads
    const int cur = kt & 1;
    if (kt + 1 < 16) {
      const int nxt = cur ^ 1;
#pragma unroll
      for (int it = 0; it < 2; it++) {
        int row = srow0 + it * 32;
        int scg = sc ^ (row & 7);
        GLD16(kg + (size_t)((kt + 1) * 64 + row) * C3_ + scg * 8,
              &Ks[nxt][w * 512 + it * 2048]);
        GLD16(vg + (size_t)row * HW_ + (kt + 1) * 64 + scg * 8,
              &Vts[nxt][w * 512 + it * 2048]);
      }
    }

    // S^T = K·Q^T for both q-groups; each K fragment read used twice
    f32x4 sfr[2][4];
#pragma unroll
    for (int qg = 0; qg < 2; qg++)
#pragma unroll
      for (int nt = 0; nt < 4; nt++) sfr[qg][nt] = (f32x4){0.f, 0.f, 0.f, 0.f};
#pragma unroll
    for (int kc = 0; kc < 2; kc++) {
#pragma unroll
      for (int nt = 0; nt < 4; nt++) {
        int row = nt * 16 + lcol;
        short8 kf = *(const short8*)
            &Ks[cur][row * 64 + (((kc * 4 + quad) ^ (row & 7)) * 8)];
        sfr[0][nt] = __builtin_amdgcn_mfma_f32_16x16x32_bf16(kf, qf[0][kc],
                                                             sfr[0][nt], 0, 0, 0);
        sfr[1][nt] = __builtin_amdgcn_mfma_f32_16x16x32_bf16(kf, qf[1][kc],
                                                             sfr[1][nt], 0, 0, 0);
      }
    }

    // exp (fixed max: scores bounded ~0.07) + per-lane sum + pack P
    short4v pk[2][4];
#pragma unroll
    for (int qg = 0; qg < 2; qg++) {
#pragma unroll
      for (int nt = 0; nt < 4; nt++) {
        float f0 = __expf(sfr[qg][nt][0]);
        float f1 = __expf(sfr[qg][nt][1]);
        float f2 = __expf(sfr[qg][nt][2]);
        float f3 = __expf(sfr[qg][nt][3]);
        lsum[qg] += f0 + f1 + f2 + f3;
        pk[qg][nt] = (short4v){(short)f2bf(f0), (short)f2bf(f1),
                               (short)f2bf(f2), (short)f2bf(f3)};
      }
    }

    // O^T += V^T · P^T ; each Vt fragment read used twice
#pragma unroll
    for (int nt = 0; nt < 4; nt++) {
      int key = nt * 16 + quad * 4;
#pragma unroll
      for (int dt = 0; dt < 4; dt++) {
        int d = dt * 16 + lcol;
        short4v vf = *(const short4v*)
            &Vts[cur][d * 64 + (((key >> 3) ^ (d & 7)) * 8) + (key & 7)];
        ot[0][dt] = pv_mfma(vf, pk[0][nt], ot[0][dt]);
        ot[1][dt] = pv_mfma(vf, pk[1][nt], ot[1][dt]);
      }
    }
  }

#pragma unroll
  for (int qg = 0; qg < 2; qg++) {
    float s = lsum[qg];
    s += __shfl_xor(s, 16);
    s += __shfl_xor(s, 32);
    const float inv = 1.0f / s;
    const int m = q0 + w * 32 + qg * 16 + lcol;
    ushort* orow = o + ((size_t)(b * HW_ + m)) * C_ + h * 64;
#pragma unroll
    for (int dt = 0; dt < 4; dt++) {
      ushort4_t pkb = {f2bf(ot[qg][dt][0] * inv), f2bf(ot[qg][dt][1] * inv),
                       f2bf(ot[qg][dt][2] * inv), f2bf(ot[qg][dt][3] * inv)};
      *(ushort4_t*)&orow[dt * 16 + quad * 4] = pkb;
    }
  }
}

// -------------------------------------------------------------------------
// K5: LayerNorm, wave-per-token (no LDS, no barriers). bf16 in/out,
// residual xT bf16; writes y_bf in place over xT.
__global__ __launch_bounds__(256) void ln_residual_kernel(
    const ushort* __restrict__ po, const ushort* xT,
    const float* __restrict__ g, const float* __restrict__ bb, ushort* ybf) {
  const int wv = threadIdx.x >> 6, lane = threadIdx.x & 63;
  const int token = blockIdx.x * 4 + wv;
  const int c0 = lane * 8;
  ushort8 p8 = *(const ushort8*)&po[(size_t)token * C_ + c0];
  float v[8];
  float s = 0.f;
#pragma unroll
  for (int j = 0; j < 8; j++) {
    v[j] = bf2f(p8[j]);
    s += v[j];
  }
#pragma unroll
  for (int off = 32; off; off >>= 1) s += __shfl_xor(s, off);
  float mu = s * (1.0f / C_);
  float vs = 0.f;
#pragma unroll
  for (int j = 0; j < 8; j++) {
    v[j] -= mu;
    vs += v[j] * v[j];
  }
#pragma unroll
  for (int off = 32; off; off >>= 1) vs += __shfl_xor(vs, off);
  float rstd = rsqrtf(vs * (1.0f / C_) + 1e-5f);
  float4 g0 = *(const float4*)&g[c0], g1 = *(const float4*)&g[c0 + 4];
  float4 b0 = *(const float4*)&bb[c0], b1 = *(const float4*)&bb[c0 + 4];
  ushort8 r8 = *(const ushort8*)&xT[(size_t)token * C_ + c0];
  float gg[8] = {g0.x, g0.y, g0.z, g0.w, g1.x, g1.y, g1.z, g1.w};
  float bbv[8] = {b0.x, b0.y, b0.z, b0.w, b1.x, b1.y, b1.z, b1.w};
  ushort8 pk;
#pragma unroll
  for (int j = 0; j < 8; j++)
    pk[j] = f2bf(v[j] * rstd * gg[j] + bbv[j] + bf2f(r8[j]));
  *(ushort8*)&ybf[(size_t)token * C_ + c0] = pk;
}

// -------------------------------------------------------------------------
// K6: depthwise 3x3 SAME on bf16 y (token-major) -> bf16 out (+dw bias)
__global__ __launch_bounds__(256) void dwconv_kernel(
    const ushort* __restrict__ y, const float* __restrict__ w,
    const float* __restrict__ bias, ushort* __restrict__ out) {
  const int cg = threadIdx.x & 63, tg = threadIdx.x >> 6;
  const int c0 = cg * 8;
  float wreg[9][8], breg[8];
#pragma unroll
  for (int j = 0; j < 8; j++) {
    breg[j] = bias[c0 + j];
#pragma unroll
    for (int kk = 0; kk < 9; kk++) wreg[kk][j] = w[(c0 + j) * 9 + kk];
  }
  for (int i = 0; i < 4; i++) {
    int token = blockIdx.x * 16 + tg * 4 + i;
    int b = token >> 10, s = token & (HW_ - 1);
    int hh = s >> 5, ww = s & 31;
    float acc[8];
#pragma unroll
    for (int j = 0; j < 8; j++) acc[j] = breg[j];
#pragma unroll
    for (int ky = 0; ky < 3; ky++) {
      int yy = hh + ky - 1;
      if (yy < 0 || yy >= HH_) continue;
#pragma unroll
      for (int kx = 0; kx < 3; kx++) {
        int xx = ww + kx - 1;
        if (xx < 0 || xx >= WW_) continue;
        ushort8 v8 = *(const ushort8*)
            &y[((size_t)(b * HW_ + yy * 32 + xx)) * C_ + c0];
        const float* wk = wreg[ky * 3 + kx];
#pragma unroll
        for (int j = 0; j < 8; j++) acc[j] += wk[j] * bf2f(v8[j]);
      }
    }
    ushort8 pk;
#pragma unroll
    for (int j = 0; j < 8; j++) pk[j] = f2bf(acc[j]);
    *(ushort8*)&out[(size_t)token * C_ + c0] = pk;
  }
}

// -------------------------------------------------------------------------
extern "C" void kernel_launch(void* const* d_in, const int* in_sizes, int n_in,
                              void* d_out, int out_size, void* d_ws,
                              size_t ws_size, hipStream_t stream) {
  const float* x = (const float*)d_in[0];
  const float* qkv_w = (const float*)d_in[1];
  const float* proj_w = (const float*)d_in[2];
  const float* proj_b = (const float*)d_in[3];
  const float* temperature = (const float*)d_in[4];
  const float* ln_g = (const float*)d_in[5];
  const float* ln_b = (const float*)d_in[6];
  const float* pos = (const float*)d_in[7];
  const float* dw_w = (const float*)d_in[8];
  const float* dw_b = (const float*)d_in[9];
  const float* pw_w = (const float*)d_in[10];
  const float* pw_b = (const float*)d_in[11];
  float* out = (float*)d_out;

  float* ws = (float*)d_ws;
  ushort* qkv_bf = (ushort*)ws;
  ushort* t_bf = (ushort*)(ws + (size_t)6 * 1024 * 1024);
  ushort* proj_bf = (ushort*)(ws + (size_t)8 * 1024 * 1024);
  ushort* xT_bf = (ushort*)(ws + (size_t)12 * 1024 * 1024);
  ushort* wts = (ushort*)(ws + (size_t)14 * 1024 * 1024);
  ushort* qkvw_bf = wts;
  ushort* projw_bf = wts + 786432;
  ushort* pww_bf = wts + 1048576;
  float* sums = ws + (size_t)15 * 1024 * 1024;
  float* qsum = sums;
  float* ksum = sums + 4096;
  ushort* vtb = (ushort*)(ws + (size_t)16 * 1024 * 1024);

  const int M = BB_ * HW_;  // 8192 tokens

  // 1) prep: weights->bf16, t/xT transpose, zero sums
  prep_kernel<<<6176, 256, 0, stream>>>(x, pos, qkv_w, proj_w, pw_w, t_bf,
                                        xT_bf, wts, sums);
  // 2) qkv GEMM: q/k bf16 + norm-sums; V -> vt transposed
  gemm_qkv<<<dim3(C3_ / 128, M / 128), 256, 0, stream>>>(
      t_bf, qkvw_bf, qkv_bf, vtb, qsum, ksum);
  // 3) flash attention (128q/block, bh-minor XCD-local order) -> attn_out
  attn_mfma_kernel<<<BB_ * NH_ * (HW_ / 128), 256, 0, stream>>>(
      qkv_bf, vtb, qsum, ksum, temperature, t_bf);
  // 4) proj GEMM (+bias, bf16 out)
  gemm_n64<1><<<dim3(C_ / 64, M / 128), 256, 0, stream>>>(
      t_bf, projw_bf, proj_b, proj_bf, nullptr, C_, C_);
  // 5) LayerNorm + residual(xT) -> y_bf (in place over xT), wave-per-token
  ln_residual_kernel<<<M / 4, 256, 0, stream>>>(proj_bf, xT_bf, ln_g, ln_b,
                                                xT_bf);
  // 6) depthwise 3x3 on bf16 y -> dw_out (bf16, reuses t region)
  dwconv_kernel<<<M / 16, 256, 0, stream>>>(xT_bf, dw_w, dw_b, t_bf);
  // 7) pointwise GEMM + pw_b + residual(y_bf), NCHW -> out
  gemm_n64<2><<<dim3(C_ / 64, M / 128), 256, 0, stream>>>(
      t_bf, pww_bf, pw_b, out, xT_bf, C_, C_);
}